// Round 8
// baseline (237.154 us; speedup 1.0000x reference)
//
#include <hip/hip_runtime.h>
#include <math.h>

#define B_   4
#define S_   2048
#define E_   256
#define H_   8
#define DK_  32
#define NROWS (B_*S_)   // 8192

typedef unsigned short ushort_t;
typedef __attribute__((ext_vector_type(8))) short  bf16x8;
typedef __attribute__((ext_vector_type(4))) float  f32x4;

#define LOG2E 1.4426950408889634f
#define QSCALE (0.17677669529663687f * 1.4426950408889634f)   // 1/sqrt(32) * log2(e)

#if __has_builtin(__builtin_amdgcn_exp2f)
#define EXP2F(x) __builtin_amdgcn_exp2f(x)
#else
#define EXP2F(x) exp2f(x)
#endif
#if __has_builtin(__builtin_amdgcn_sqrtf)
#define SQRTF(x) __builtin_amdgcn_sqrtf(x)
#else
#define SQRTF(x) sqrtf(x)
#endif
#if __has_builtin(__builtin_amdgcn_rcpf)
#define RCPF(x) __builtin_amdgcn_rcpf(x)
#else
#define RCPF(x) (1.0f/(x))
#endif

__device__ __forceinline__ ushort_t bf16_rne(float x)
{
    unsigned int u = __float_as_uint(x);
    unsigned int r = u + 0x7FFFu + ((u >> 16) & 1u);
    return (ushort_t)(r >> 16);
}
__device__ __forceinline__ float bf16_to_f(ushort_t h)
{
    return __uint_as_float(((unsigned int)h) << 16);
}

// 16-lane (DPP-row) inclusive prefix scan: 4 full-rate VALU adds.
__device__ __forceinline__ float scan16(float x)
{
    x += __int_as_float(__builtin_amdgcn_update_dpp(0, __float_as_int(x), 0x111, 0xF, 0xF, true));
    x += __int_as_float(__builtin_amdgcn_update_dpp(0, __float_as_int(x), 0x112, 0xF, 0xF, true));
    x += __int_as_float(__builtin_amdgcn_update_dpp(0, __float_as_int(x), 0x114, 0xF, 0xF, true));
    x += __int_as_float(__builtin_amdgcn_update_dpp(0, __float_as_int(x), 0x118, 0xF, 0xF, true));
    return x;
}
__device__ __forceinline__ float bcast15(float x)
{
    return __int_as_float(__builtin_amdgcn_ds_swizzle(__float_as_int(x), 0x1F0));
}

// ===========================================================================
// Fragment-swizzled layout: [rows][K] operand stored as contiguous 512-elem
// blocks (16 rows x 32 k); a wave's fragment load = base + block*512 + lane*8.
//   intra(n,k) = ((k>>3)&3)*128 + (n&15)*8 + (k&7)
// ===========================================================================

// ---------------------------------------------------------------------------
// conv: fp32 [rows][256] -> swizzled hi/lo bf16.  z<3: q,k,v; z>=3: weights.
// ---------------------------------------------------------------------------
__global__ __launch_bounds__(256)
void conv_all(const float* __restrict__ q, const float* __restrict__ k,
              const float* __restrict__ v,
              const float* __restrict__ Wq, const float* __restrict__ Wk,
              const float* __restrict__ Wv, const float* __restrict__ Wo,
              ushort_t* __restrict__ xh, ushort_t* __restrict__ xl,
              ushort_t* __restrict__ wh, ushort_t* __restrict__ wl)
{
    const int z = blockIdx.y;
    const float* src;
    ushort_t *dh, *dl;
    if (z < 3) {
        src = (z == 0) ? q : (z == 1) ? k : v;
        dh = xh + (size_t)z * (NROWS * E_);
        dl = xl + (size_t)z * (NROWS * E_);
    } else {
        if (blockIdx.x >= 16) return;
        src = (z == 3) ? Wq : (z == 4) ? Wk : (z == 5) ? Wv : Wo;
        dh = wh + (size_t)(z - 3) * (E_ * E_);
        dl = wl + (size_t)(z - 3) * (E_ * E_);
    }
    const int n0 = blockIdx.x * 16;
    const int lr = threadIdx.x & 15, kq = threadIdx.x >> 4;   // kq 0..15
    #pragma unroll
    for (int half = 0; half < 2; half++) {
        const int kk = kq * 8 + half * 128;
        const float* s = src + (size_t)(n0 + lr) * E_ + kk;
        const float4 a = *(const float4*)s;
        const float4 b = *(const float4*)(s + 4);
        const float xs[8] = {a.x, a.y, a.z, a.w, b.x, b.y, b.z, b.w};
        bf16x8 hv, lv;
        #pragma unroll
        for (int e = 0; e < 8; e++) {
            const ushort_t hb = bf16_rne(xs[e]);
            hv[e] = (short)hb;
            lv[e] = (short)bf16_rne(xs[e] - bf16_to_f(hb));
        }
        const size_t o = ((size_t)blockIdx.x * 8 + (kk >> 5)) * 512
                       + ((kk >> 3) & 3) * 128 + lr * 8;
        *(bf16x8*)&dh[o] = hv;
        *(bf16x8*)&dl[o] = lv;
    }
}

// ---------------------------------------------------------------------------
// m97-lite MFMA GEMM: A fragments direct from global (swizzled, in-register
// prefetch); B staged cooperatively through DOUBLE-BUFFERED LDS (16 KB),
// one barrier per K-chunk. Block = 4 waves = 4 n-strips x 64 m-cols.
// mode 1: Q (scaled hi/lo)  mode 2: K (hi/lo)  mode 3: V (B-frag bf16)
// mode 0: fp32 out.
// ---------------------------------------------------------------------------
__device__ __forceinline__ void gemm_lds_core(
    const ushort_t* __restrict__ Ah, const ushort_t* __restrict__ Al,
    const ushort_t* __restrict__ Bh, const ushort_t* __restrict__ Bl,
    int nstrip, int mb, int wv, int lane,
    ushort_t* __restrict__ sBh, ushort_t* __restrict__ sBl,   // [2][2048] each
    f32x4 (&acc)[4])
{
    const size_t aoff = (size_t)nstrip * 8 * 512 + lane * 8;
    const size_t boff = (size_t)(mb * 4 + wv) * 8 * 512 + lane * 8;
    const int lw = wv * 512 + lane * 8;          // staging slot (elems)

    bf16x8 aH = *(const bf16x8*)(Ah + aoff);
    bf16x8 aL = *(const bf16x8*)(Al + aoff);
    {
        const bf16x8 sH = *(const bf16x8*)(Bh + boff);
        const bf16x8 sL = *(const bf16x8*)(Bl + boff);
        *(bf16x8*)&sBh[lw] = sH;
        *(bf16x8*)&sBl[lw] = sL;
    }

    #pragma unroll
    for (int kc = 0; kc < 8; kc++) {
        __syncthreads();                         // buf[kc&1] ready for all
        const int cur = (kc & 1) * 2048;
        bf16x8 aH2, aL2, sH2, sL2;
        if (kc < 7) {
            aH2 = *(const bf16x8*)(Ah + aoff + (size_t)(kc + 1) * 512);
            aL2 = *(const bf16x8*)(Al + aoff + (size_t)(kc + 1) * 512);
            sH2 = *(const bf16x8*)(Bh + boff + (size_t)(kc + 1) * 512);
            sL2 = *(const bf16x8*)(Bl + boff + (size_t)(kc + 1) * 512);
        }
        #pragma unroll
        for (int t = 0; t < 4; t++) {
            const int ro = cur + t * 512 + lane * 8;
            const bf16x8 bH = *(const bf16x8*)&sBh[ro];
            const bf16x8 bL = *(const bf16x8*)&sBl[ro];
            acc[t] = __builtin_amdgcn_mfma_f32_16x16x32_bf16(aL, bH, acc[t], 0, 0, 0);
            acc[t] = __builtin_amdgcn_mfma_f32_16x16x32_bf16(aH, bL, acc[t], 0, 0, 0);
            acc[t] = __builtin_amdgcn_mfma_f32_16x16x32_bf16(aH, bH, acc[t], 0, 0, 0);
        }
        if (kc < 7) {
            const int nx = (cur ^ 2048) + lw;    // other buffer; safe after barrier
            *(bf16x8*)&sBh[nx] = sH2;
            *(bf16x8*)&sBl[nx] = sL2;
            aH = aH2; aL = aL2;
        }
    }
}

__global__ __launch_bounds__(256)
void gemm_qkv(const ushort_t* __restrict__ Xh, const ushort_t* __restrict__ Xl,
              const ushort_t* __restrict__ Wh, const ushort_t* __restrict__ Wl,
              const float* __restrict__ bqp, const float* __restrict__ bkp,
              const float* __restrict__ bvp,
              ushort_t* __restrict__ Qh, ushort_t* __restrict__ Ql,
              ushort_t* __restrict__ Kh, ushort_t* __restrict__ Kl,
              ushort_t* __restrict__ Vt)
{
    __shared__ __align__(16) ushort_t sBh[2 * 2048];
    __shared__ __align__(16) ushort_t sBl[2 * 2048];

    const size_t N2 = (size_t)NROWS * E_;
    const size_t WN = (size_t)E_ * E_;
    const int z = blockIdx.z;
    const ushort_t* Ah = Xh + (size_t)z * N2;
    const ushort_t* Al = Xl + (size_t)z * N2;
    const ushort_t* Bh = Wh + (size_t)z * WN;
    const ushort_t* Bl = Wl + (size_t)z * WN;
    const float* bias = (z == 0) ? bqp : (z == 1) ? bkp : bvp;
    const float scale = (z == 0) ? QSCALE : 1.0f;

    const int lane = threadIdx.x & 63, wv = threadIdx.x >> 6;
    const int lr = lane & 15, lq = lane >> 4;
    const int mb = blockIdx.x;
    const int nstrip = blockIdx.y * 4 + wv;

    f32x4 acc[4] = {{0,0,0,0},{0,0,0,0},{0,0,0,0},{0,0,0,0}};
    gemm_lds_core(Ah, Al, Bh, Bl, nstrip, mb, wv, lane, sBh, sBl, acc);

    #pragma unroll
    for (int t = 0; t < 4; t++) {
        const int col = mb * 64 + t * 16 + lr;
        const float bt = bias[col];
        const int h = col >> 5, d = col & 31;
        if (z <= 1) {                           // Q/K -> attn frag layout hi/lo
            ushort_t* Y1 = (z == 0) ? Qh : Kh;
            ushort_t* Y2 = (z == 0) ? Ql : Kl;
            #pragma unroll
            for (int reg = 0; reg < 4; reg++) {
                const int n  = nstrip * 16 + lq * 4 + reg;
                const int bI = n >> 11, sI = n & (S_ - 1);
                const size_t o = (size_t)(bI * H_ + h) * (S_ * DK_)
                               + (size_t)(sI >> 4) * 512
                               + ((d >> 3) & 3) * 128 + (sI & 15) * 8 + (d & 7);
                const float y = (acc[t][reg] + bt) * scale;
                const ushort_t hb = bf16_rne(y);
                Y1[o] = hb;
                Y2[o] = bf16_rne(y - bf16_to_f(hb));
            }
        } else {                                // V -> attn B-frag layout
            #pragma unroll
            for (int reg = 0; reg < 4; reg++) {
                const int n  = nstrip * 16 + lq * 4 + reg;
                const int bI = n >> 11, sI = n & (S_ - 1);
                const size_t o = (size_t)(bI * H_ + h) * (S_ * DK_)
                               + (size_t)((sI >> 5) * 2 + (d >> 4)) * 512
                               + ((sI >> 3) & 3) * 128 + (d & 15) * 8 + (sI & 7);
                Vt[o] = bf16_rne(acc[t][reg] + bt);
            }
        }
    }
}

__global__ __launch_bounds__(256)
void gemm_out(const ushort_t* __restrict__ Xh, const ushort_t* __restrict__ Xl,
              const ushort_t* __restrict__ Wh, const ushort_t* __restrict__ Wl,
              const float* __restrict__ bias, float* __restrict__ Yf)
{
    __shared__ __align__(16) ushort_t sBh[2 * 2048];
    __shared__ __align__(16) ushort_t sBl[2 * 2048];

    const int lane = threadIdx.x & 63, wv = threadIdx.x >> 6;
    const int lr = lane & 15, lq = lane >> 4;
    const int mb = blockIdx.x;
    const int nstrip = blockIdx.y * 4 + wv;

    f32x4 acc[4] = {{0,0,0,0},{0,0,0,0},{0,0,0,0},{0,0,0,0}};
    gemm_lds_core(Xh, Xl, Wh, Wl, nstrip, mb, wv, lane, sBh, sBl, acc);

    #pragma unroll
    for (int t = 0; t < 4; t++) {
        const int col = mb * 64 + t * 16 + lr;
        const float bt = bias[col];
        #pragma unroll
        for (int reg = 0; reg < 4; reg++) {
            const int n = nstrip * 16 + lq * 4 + reg;
            Yf[(size_t)n * E_ + col] = acc[t][reg] + bt;
        }
    }
}

// ---------------------------------------------------------------------------
// Flash decay attention (round 6 structure; clamp dropped, posf incremental).
// ---------------------------------------------------------------------------
#define VPAD 72

__device__ __forceinline__ void score_tile(f32x4 (&a)[4],
    const ushort_t* __restrict__ Kbh, const ushort_t* __restrict__ Kbl,
    int jt, const bf16x8& qhi, const bf16x8& qlo, int lane, int lr, int lq,
    bool domask, int i0)
{
    #pragma unroll
    for (int tt = 0; tt < 4; tt++) {
        const size_t ko = (size_t)(jt * 4 + tt) * 512 + lane * 8;
        const bf16x8 khi = *(const bf16x8*)(Kbh + ko);
        const bf16x8 klo = *(const bf16x8*)(Kbl + ko);
        f32x4 v = {0.f, 0.f, 0.f, 0.f};
        v = __builtin_amdgcn_mfma_f32_16x16x32_bf16(qlo, khi, v, 0, 0, 0);
        v = __builtin_amdgcn_mfma_f32_16x16x32_bf16(qhi, klo, v, 0, 0, 0);
        v = __builtin_amdgcn_mfma_f32_16x16x32_bf16(qhi, khi, v, 0, 0, 0);
        a[tt] = v;
    }
    if (domask) {
        #pragma unroll
        for (int tt = 0; tt < 4; tt++)
            #pragma unroll
            for (int r = 0; r < 4; r++) {
                const int irow = i0 + lq * 4 + r;
                const int j    = jt * 64 + tt * 16 + lr;
                if (j > irow) a[tt][r] = -3.0e38f;
            }
    }
}

__global__ __launch_bounds__(256)
void attn_flash(const ushort_t* __restrict__ Qh, const ushort_t* __restrict__ Ql,
                const ushort_t* __restrict__ Kh, const ushort_t* __restrict__ Kl,
                const ushort_t* __restrict__ Vs, const float* __restrict__ gammas,
                ushort_t* __restrict__ Ch, ushort_t* __restrict__ Cl)
{
    __shared__ float sTS[16][36];
    __shared__ __align__(16) ushort_t sP[4][16 * VPAD];
    __shared__ float sO[4][16][32];
    __shared__ float sZ[4][16];

    const int tid  = threadIdx.x;
    const int lane = tid & 63, wv = tid >> 6;
    const int lr   = lane & 15, lq = lane >> 4;
    const int unit = blockIdx.x >> 7;
    const int tq   = 31 - unit;
    const int sub  = blockIdx.x & 127;
    const int bh   = sub & 31;
    const int st   = sub >> 5;
    const int h    = bh & 7, b = bh >> 3;
    const int i0   = tq * 64 + st * 16;

    const size_t hb = (size_t)bh * (S_ * DK_);
    const ushort_t* Kbh = Kh + hb;
    const ushort_t* Kbl = Kl + hb;
    const ushort_t* Vb  = Vs + hb;

    const float g   = gammas[h];
    const float gl2 = -((g > 20.f) ? g : log1pf(__expf(g))) * LOG2E;

    const size_t qoff = hb + (size_t)(i0 >> 4) * 512 + lane * 8;
    const bf16x8 qhi = *(const bf16x8*)(Qh + qoff);
    const bf16x8 qlo = *(const bf16x8*)(Ql + qoff);

    // ================= PASS A: per-tile raw exp row-sums ==================
    for (int jt = wv; jt <= tq; jt += 4) {
        f32x4 a[4];
        score_tile(a, Kbh, Kbl, jt, qhi, qlo, lane, lr, lq, jt == tq, i0);
        #pragma unroll
        for (int r = 0; r < 4; r++) {
            float rs = (EXP2F(a[0][r]) + EXP2F(a[1][r]))
                     + (EXP2F(a[2][r]) + EXP2F(a[3][r]));
            rs += __shfl_xor(rs, 1); rs += __shfl_xor(rs, 2);
            rs += __shfl_xor(rs, 4); rs += __shfl_xor(rs, 8);
            if (lr == 0) sTS[lq * 4 + r][jt] = rs;
        }
    }
    __syncthreads();

    // ================= PASS B (barrier-free per wave) =====================
    float z2a[4] = {0.f, 0.f, 0.f, 0.f};
    f32x4 O0 = {0.f,0.f,0.f,0.f}, O1 = {0.f,0.f,0.f,0.f};

    if (wv <= tq) {
        float invZ[4], base[4], pr[4];
        #pragma unroll
        for (int r = 0; r < 4; r++) {
            const int row = lq * 4 + r;
            float run = 0.f, bs = 0.f;
            for (int t = 0; t <= tq; t++) {
                if (t < wv) bs += sTS[row][t];
                run += sTS[row][t];
            }
            invZ[r] = RCPF(run);
            base[r] = bs;
            pr[r]   = (float)(i0 + row - lr);    // posf = pr - (j0 + tt*16)
        }

        ushort_t* sPw = &sP[wv][0];
        for (int jt = wv; jt <= tq; jt += 4) {
            const int j0 = jt * 64;
            f32x4 a[4];
            score_tile(a, Kbh, Kbl, jt, qhi, qlo, lane, lr, lq, jt == tq, i0);

            float sc[4][4], tot[4][4];
            #pragma unroll
            for (int tt = 0; tt < 4; tt++)
                #pragma unroll
                for (int r = 0; r < 4; r++) {
                    const float e = EXP2F(a[tt][r]);
                    const float s = scan16(e);
                    sc[tt][r]  = s;
                    tot[tt][r] = bcast15(s);
                }
            #pragma unroll
            for (int r = 0; r < 4; r++) {
                float run2 = base[r];
                #pragma unroll
                for (int tt = 0; tt < 4; tt++) { sc[tt][r] += run2; run2 += tot[tt][r]; }
            }
            #pragma unroll
            for (int tt = 0; tt < 4; tt++) {
                const float jf = (float)(j0 + tt * 16);
                #pragma unroll
                for (int r = 0; r < 4; r++) {
                    const float rest = fmaxf(fmaf(-sc[tt][r], invZ[r], 1.0f), 0.f);
                    const float posf = pr[r] - jf;
                    const float dist = SQRTF(fmaxf(rest * posf, 0.f));
                    const float eff  = EXP2F(gl2 * dist);       // clamp dropped: <=3e-4 rel err
                    const float p2   = EXP2F(a[tt][r] * eff);
                    z2a[r] += p2;
                    sPw[(lq * 4 + r) * VPAD + tt * 16 + lr] = bf16_rne(p2);
                }
            }
            #pragma unroll
            for (int kc = 0; kc < 2; kc++) {
                const bf16x8 pa = *(const bf16x8*)&sPw[lr * VPAD + kc * 32 + lq * 8];
                const size_t vb = (size_t)(((j0 >> 5) + kc) * 2) * 512 + lane * 8;
                const bf16x8 v0 = *(const bf16x8*)(Vb + vb);
                const bf16x8 v1 = *(const bf16x8*)(Vb + vb + 512);
                O0 = __builtin_amdgcn_mfma_f32_16x16x32_bf16(pa, v0, O0, 0, 0, 0);
                O1 = __builtin_amdgcn_mfma_f32_16x16x32_bf16(pa, v1, O1, 0, 0, 0);
            }
            if (jt + 4 <= tq) {
                #pragma unroll
                for (int r = 0; r < 4; r++) {
                    const int row = lq * 4 + r;
                    base[r] += sTS[row][jt] + sTS[row][jt+1] + sTS[row][jt+2] + sTS[row][jt+3];
                }
            }
        }
    }

    // ================= cross-wave reduce + output =========================
    #pragma unroll
    for (int r = 0; r < 4; r++) {
        float z = z2a[r];
        z += __shfl_xor(z, 1); z += __shfl_xor(z, 2);
        z += __shfl_xor(z, 4); z += __shfl_xor(z, 8);
        if (lr == 0) sZ[wv][lq * 4 + r] = z;
        sO[wv][lq * 4 + r][lr]      = O0[r];
        sO[wv][lq * 4 + r][16 + lr] = O1[r];
    }
    __syncthreads();

    #pragma unroll
    for (int p = 0; p < 2; p++) {
        const int pid = tid + p * 256;
        const int row = pid >> 5, d = pid & 31;
        const float v = (sO[0][row][d] + sO[1][row][d]) + (sO[2][row][d] + sO[3][row][d]);
        const float z = (sZ[0][row] + sZ[1][row]) + (sZ[2][row] + sZ[3][row]);
        const float y = v * RCPF(z);
        const int nIdx = b * S_ + i0 + row;
        const size_t o = ((size_t)(nIdx >> 4) * 8 + h) * 512
                       + (d >> 3) * 128 + (nIdx & 15) * 8 + (d & 7);
        const ushort_t hbb = bf16_rne(y);
        Ch[o] = hbb;
        Cl[o] = bf16_rne(y - bf16_to_f(hbb));
    }
}

// ---------------------------------------------------------------------------
extern "C" void kernel_launch(void* const* d_in, const int* in_sizes, int n_in,
                              void* d_out, int out_size, void* d_ws, size_t ws_size,
                              hipStream_t stream)
{
    const float* q      = (const float*)d_in[0];
    const float* k      = (const float*)d_in[1];
    const float* v      = (const float*)d_in[2];
    // d_in[3] = causal mask (analytic; unused)
    const float* Wq     = (const float*)d_in[4];
    const float* bq     = (const float*)d_in[5];
    const float* Wk     = (const float*)d_in[6];
    const float* bk     = (const float*)d_in[7];
    const float* Wv     = (const float*)d_in[8];
    const float* bv     = (const float*)d_in[9];
    const float* Wo     = (const float*)d_in[10];
    const float* bo     = (const float*)d_in[11];
    const float* gammas = (const float*)d_in[12];
    float* out = (float*)d_out;

    const size_t N2 = (size_t)NROWS * E_;      // 2,097,152 elements
    const size_t WN = (size_t)E_ * E_;         // 65,536

    ushort_t* p   = (ushort_t*)d_ws;
    ushort_t* xh  = p;                         // 3*N2 (inputs hi)
    ushort_t* xl  = xh + 3 * N2;               // 3*N2 (inputs lo)
    ushort_t* wh  = xl + 3 * N2;               // 4*WN
    ushort_t* wl  = wh + 4 * WN;               // 4*WN
    ushort_t* qh  = wl + 4 * WN;
    ushort_t* ql  = qh + N2;
    ushort_t* kh  = ql + N2;
    ushort_t* kl  = kh + N2;
    ushort_t* vt  = kl + N2;
    // concat aliases the (dead after projections) input-conversion region
    ushort_t* ch  = xh;
    ushort_t* cl  = xh + N2;

    conv_all<<<dim3(NROWS / 16, 7), 256, 0, stream>>>(q, k, v, Wq, Wk, Wv, Wo,
                                                      xh, xl, wh, wl);

    gemm_qkv<<<dim3(E_ / 64, NROWS / 64, 3), 256, 0, stream>>>(
        xh, xl, wh, wl, bq, bk, bv, qh, ql, kh, kl, vt);

    attn_flash<<<32 * 32 * 4, 256, 0, stream>>>(qh, ql, kh, kl, vt, gammas, ch, cl);

    gemm_out<<<dim3(E_ / 64, NROWS / 64), 256, 0, stream>>>(
        ch, cl, wh + 3 * WN, wl + 3 * WN, bo, out);
}

// Round 9
// 230.049 us; speedup vs baseline: 1.0309x; 1.0309x over previous
//
#include <hip/hip_runtime.h>
#include <math.h>

#define B_   4
#define S_   2048
#define E_   256
#define H_   8
#define DK_  32
#define NROWS (B_*S_)   // 8192

typedef unsigned short ushort_t;
typedef __attribute__((ext_vector_type(8))) short  bf16x8;
typedef __attribute__((ext_vector_type(4))) float  f32x4;

#define LOG2E 1.4426950408889634f
#define QSCALE (0.17677669529663687f * 1.4426950408889634f)   // 1/sqrt(32) * log2(e)

#if __has_builtin(__builtin_amdgcn_exp2f)
#define EXP2F(x) __builtin_amdgcn_exp2f(x)
#else
#define EXP2F(x) exp2f(x)
#endif
#if __has_builtin(__builtin_amdgcn_sqrtf)
#define SQRTF(x) __builtin_amdgcn_sqrtf(x)
#else
#define SQRTF(x) sqrtf(x)
#endif
#if __has_builtin(__builtin_amdgcn_rcpf)
#define RCPF(x) __builtin_amdgcn_rcpf(x)
#else
#define RCPF(x) (1.0f/(x))
#endif

__device__ __forceinline__ ushort_t bf16_rne(float x)
{
    unsigned int u = __float_as_uint(x);
    unsigned int r = u + 0x7FFFu + ((u >> 16) & 1u);
    return (ushort_t)(r >> 16);
}
__device__ __forceinline__ float bf16_to_f(ushort_t h)
{
    return __uint_as_float(((unsigned int)h) << 16);
}

// 16-lane (DPP-row) inclusive prefix scan: 4 full-rate VALU adds.
__device__ __forceinline__ float scan16(float x)
{
    x += __int_as_float(__builtin_amdgcn_update_dpp(0, __float_as_int(x), 0x111, 0xF, 0xF, true));
    x += __int_as_float(__builtin_amdgcn_update_dpp(0, __float_as_int(x), 0x112, 0xF, 0xF, true));
    x += __int_as_float(__builtin_amdgcn_update_dpp(0, __float_as_int(x), 0x114, 0xF, 0xF, true));
    x += __int_as_float(__builtin_amdgcn_update_dpp(0, __float_as_int(x), 0x118, 0xF, 0xF, true));
    return x;
}
__device__ __forceinline__ float bcast15(float x)
{
    return __int_as_float(__builtin_amdgcn_ds_swizzle(__float_as_int(x), 0x1F0));
}

// ===========================================================================
// Fragment-swizzled layout: [rows][K] operand stored as contiguous 512-elem
// blocks (16 rows x 32 k); a wave's fragment load = base + block*512 + lane*8.
//   intra(n,k) = ((k>>3)&3)*128 + (n&15)*8 + (k&7)   == lane*8 for A/B frags
// ===========================================================================

// ---------------------------------------------------------------------------
// Weights only: fp32 [256][256] -> swizzled hi/lo bf16 (4 matrices).
// ---------------------------------------------------------------------------
__global__ __launch_bounds__(256)
void conv_w(const float* __restrict__ Wq, const float* __restrict__ Wk,
            const float* __restrict__ Wv, const float* __restrict__ Wo,
            ushort_t* __restrict__ wh, ushort_t* __restrict__ wl)
{
    const int z = blockIdx.y;
    const float* src = (z == 0) ? Wq : (z == 1) ? Wk : (z == 2) ? Wv : Wo;
    ushort_t* dh = wh + (size_t)z * (E_ * E_);
    ushort_t* dl = wl + (size_t)z * (E_ * E_);
    const int n0 = blockIdx.x * 16;
    const int lr = threadIdx.x & 15, kq = threadIdx.x >> 4;   // kq 0..15
    #pragma unroll
    for (int half = 0; half < 2; half++) {
        const int kk = kq * 8 + half * 128;
        const float* s = src + (size_t)(n0 + lr) * E_ + kk;
        const float4 a = *(const float4*)s;
        const float4 b = *(const float4*)(s + 4);
        const float xs[8] = {a.x, a.y, a.z, a.w, b.x, b.y, b.z, b.w};
        bf16x8 hv, lv;
        #pragma unroll
        for (int e = 0; e < 8; e++) {
            const ushort_t hb = bf16_rne(xs[e]);
            hv[e] = (short)hb;
            lv[e] = (short)bf16_rne(xs[e] - bf16_to_f(hb));
        }
        const size_t o = ((size_t)blockIdx.x * 8 + (kk >> 5)) * 512
                       + ((kk >> 3) & 3) * 128 + lr * 8;
        *(bf16x8*)&dh[o] = hv;
        *(bf16x8*)&dl[o] = lv;
    }
}

// ---------------------------------------------------------------------------
// Fused QKV projection: reads RAW fp32 inputs (hi/lo split in registers),
// B (weights) through double-buffered LDS, one barrier per K-chunk.
// Q/K epilogue: LDS transpose -> fully coalesced 16B/lane hi/lo stores.
// V epilogue: scalar stores into attn B-frag layout.
// ---------------------------------------------------------------------------
__global__ __launch_bounds__(256)
void gemm_qkv(const float* __restrict__ Xq, const float* __restrict__ Xk,
              const float* __restrict__ Xv,
              const ushort_t* __restrict__ Wh, const ushort_t* __restrict__ Wl,
              const float* __restrict__ bqp, const float* __restrict__ bkp,
              const float* __restrict__ bvp,
              ushort_t* __restrict__ Qh, ushort_t* __restrict__ Ql,
              ushort_t* __restrict__ Kh, ushort_t* __restrict__ Kl,
              ushort_t* __restrict__ Vt)
{
    __shared__ __align__(16) float sF[4][16][68];       // 17408 B (union below)
    ushort_t* sBh = (ushort_t*)&sF[0][0][0];            // [2][2048] ushorts
    ushort_t* sBl = sBh + 4096;                         // next 8 KB

    const size_t WN = (size_t)E_ * E_;
    const int z = blockIdx.z;
    const float* Xf = (z == 0) ? Xq : (z == 1) ? Xk : Xv;
    const ushort_t* Bh = Wh + (size_t)z * WN;
    const ushort_t* Bl = Wl + (size_t)z * WN;
    const float* bias = (z == 0) ? bqp : (z == 1) ? bkp : bvp;
    const float scale = (z == 0) ? QSCALE : 1.0f;

    const int lane = threadIdx.x & 63, wv = threadIdx.x >> 6;
    const int lr = lane & 15, lq = lane >> 4;
    const int mb = blockIdx.x;
    const int nstrip = blockIdx.y * 4 + wv;

    const float* arow = Xf + (size_t)(nstrip * 16 + lr) * E_ + lq * 8;
    const size_t boff = (size_t)(mb * 4 + wv) * 8 * 512 + lane * 8;
    const int lw = wv * 512 + lane * 8;

    f32x4 acc[4] = {{0,0,0,0},{0,0,0,0},{0,0,0,0},{0,0,0,0}};

    float4 a0 = *(const float4*)(arow);
    float4 a1 = *(const float4*)(arow + 4);
    {
        const bf16x8 sH = *(const bf16x8*)(Bh + boff);
        const bf16x8 sL = *(const bf16x8*)(Bl + boff);
        *(bf16x8*)&sBh[lw] = sH;
        *(bf16x8*)&sBl[lw] = sL;
    }

    #pragma unroll
    for (int kc = 0; kc < 8; kc++) {
        __syncthreads();
        const int cur = (kc & 1) * 2048;
        float4 a0n, a1n; bf16x8 sH2, sL2;
        if (kc < 7) {
            a0n = *(const float4*)(arow + (kc + 1) * 32);
            a1n = *(const float4*)(arow + (kc + 1) * 32 + 4);
            sH2 = *(const bf16x8*)(Bh + boff + (size_t)(kc + 1) * 512);
            sL2 = *(const bf16x8*)(Bl + boff + (size_t)(kc + 1) * 512);
        }
        // hi/lo split of current A chunk
        bf16x8 aH, aL;
        {
            const float xs[8] = {a0.x, a0.y, a0.z, a0.w, a1.x, a1.y, a1.z, a1.w};
            #pragma unroll
            for (int e = 0; e < 8; e++) {
                const ushort_t hb = bf16_rne(xs[e]);
                aH[e] = (short)hb;
                aL[e] = (short)bf16_rne(xs[e] - bf16_to_f(hb));
            }
        }
        #pragma unroll
        for (int t = 0; t < 4; t++) {
            const int ro = cur + t * 512 + lane * 8;
            const bf16x8 bH = *(const bf16x8*)&sBh[ro];
            const bf16x8 bL = *(const bf16x8*)&sBl[ro];
            acc[t] = __builtin_amdgcn_mfma_f32_16x16x32_bf16(aL, bH, acc[t], 0, 0, 0);
            acc[t] = __builtin_amdgcn_mfma_f32_16x16x32_bf16(aH, bL, acc[t], 0, 0, 0);
            acc[t] = __builtin_amdgcn_mfma_f32_16x16x32_bf16(aH, bH, acc[t], 0, 0, 0);
        }
        if (kc < 7) {
            const int nx = (cur ^ 2048) + lw;
            *(bf16x8*)&sBh[nx] = sH2;
            *(bf16x8*)&sBl[nx] = sL2;
            a0 = a0n; a1 = a1n;
        }
    }
    __syncthreads();    // staging LDS dead; sF reuse is safe

    if (z <= 1) {
        // ---- coalesced transpose epilogue (wave-private LDS region) ----
        #pragma unroll
        for (int t = 0; t < 4; t++) {
            const float bt = bias[mb * 64 + t * 16 + lr];
            #pragma unroll
            for (int reg = 0; reg < 4; reg++)
                sF[wv][lq * 4 + reg][t * 16 + lr] = (acc[t][reg] + bt) * scale;
        }
        ushort_t* Y1 = z ? Kh : Qh;
        ushort_t* Y2 = z ? Kl : Ql;
        const int bI   = nstrip >> 7;
        const int sblk = nstrip & 127;
        const int qg = lane >> 4, s = lane & 15;
        #pragma unroll
        for (int cg = 0; cg < 2; cg++) {
            const float* src = &sF[wv][s][cg * 32 + qg * 8];
            const float4 v0 = *(const float4*)src;
            const float4 v1 = *(const float4*)(src + 4);
            const float xs[8] = {v0.x, v0.y, v0.z, v0.w, v1.x, v1.y, v1.z, v1.w};
            bf16x8 hv, lv;
            #pragma unroll
            for (int e = 0; e < 8; e++) {
                const ushort_t hb = bf16_rne(xs[e]);
                hv[e] = (short)hb;
                lv[e] = (short)bf16_rne(xs[e] - bf16_to_f(hb));
            }
            const int h = mb * 2 + cg;
            const size_t o = (size_t)(bI * H_ + h) * (S_ * DK_)
                           + (size_t)sblk * 512 + lane * 8;
            *(bf16x8*)&Y1[o] = hv;
            *(bf16x8*)&Y2[o] = lv;
        }
    } else {
        // ---- V -> attn B-frag layout (scalar stores) ----
        #pragma unroll
        for (int t = 0; t < 4; t++) {
            const int col = mb * 64 + t * 16 + lr;
            const float bt = bias[col];
            const int h = col >> 5, d = col & 31;
            #pragma unroll
            for (int reg = 0; reg < 4; reg++) {
                const int n  = nstrip * 16 + lq * 4 + reg;
                const int bI = n >> 11, sI = n & (S_ - 1);
                const size_t o = (size_t)(bI * H_ + h) * (S_ * DK_)
                               + (size_t)((sI >> 5) * 2 + (d >> 4)) * 512
                               + ((sI >> 3) & 3) * 128 + (d & 15) * 8 + (sI & 7);
                Vt[o] = bf16_rne(acc[t][reg] + bt);
            }
        }
    }
}

// ---------------------------------------------------------------------------
// Output projection: A (concat hi/lo, pre-swizzled) direct from global,
// B through double-buffered LDS. fp32 out.
// ---------------------------------------------------------------------------
__global__ __launch_bounds__(256)
void gemm_out(const ushort_t* __restrict__ Xh, const ushort_t* __restrict__ Xl,
              const ushort_t* __restrict__ Wh, const ushort_t* __restrict__ Wl,
              const float* __restrict__ bias, float* __restrict__ Yf)
{
    __shared__ __align__(16) ushort_t sBh[2 * 2048];
    __shared__ __align__(16) ushort_t sBl[2 * 2048];

    const int lane = threadIdx.x & 63, wv = threadIdx.x >> 6;
    const int lr = lane & 15, lq = lane >> 4;
    const int mb = blockIdx.x;
    const int nstrip = blockIdx.y * 4 + wv;

    const size_t aoff = (size_t)nstrip * 8 * 512 + lane * 8;
    const size_t boff = (size_t)(mb * 4 + wv) * 8 * 512 + lane * 8;
    const int lw = wv * 512 + lane * 8;

    f32x4 acc[4] = {{0,0,0,0},{0,0,0,0},{0,0,0,0},{0,0,0,0}};

    bf16x8 aH = *(const bf16x8*)(Xh + aoff);
    bf16x8 aL = *(const bf16x8*)(Xl + aoff);
    {
        const bf16x8 sH = *(const bf16x8*)(Wh + boff);
        const bf16x8 sL = *(const bf16x8*)(Wl + boff);
        *(bf16x8*)&sBh[lw] = sH;
        *(bf16x8*)&sBl[lw] = sL;
    }

    #pragma unroll
    for (int kc = 0; kc < 8; kc++) {
        __syncthreads();
        const int cur = (kc & 1) * 2048;
        bf16x8 aH2, aL2, sH2, sL2;
        if (kc < 7) {
            aH2 = *(const bf16x8*)(Xh + aoff + (size_t)(kc + 1) * 512);
            aL2 = *(const bf16x8*)(Xl + aoff + (size_t)(kc + 1) * 512);
            sH2 = *(const bf16x8*)(Wh + boff + (size_t)(kc + 1) * 512);
            sL2 = *(const bf16x8*)(Wl + boff + (size_t)(kc + 1) * 512);
        }
        #pragma unroll
        for (int t = 0; t < 4; t++) {
            const int ro = cur + t * 512 + lane * 8;
            const bf16x8 bH = *(const bf16x8*)&sBh[ro];
            const bf16x8 bL = *(const bf16x8*)&sBl[ro];
            acc[t] = __builtin_amdgcn_mfma_f32_16x16x32_bf16(aL, bH, acc[t], 0, 0, 0);
            acc[t] = __builtin_amdgcn_mfma_f32_16x16x32_bf16(aH, bL, acc[t], 0, 0, 0);
            acc[t] = __builtin_amdgcn_mfma_f32_16x16x32_bf16(aH, bH, acc[t], 0, 0, 0);
        }
        if (kc < 7) {
            const int nx = (cur ^ 2048) + lw;
            *(bf16x8*)&sBh[nx] = sH2;
            *(bf16x8*)&sBl[nx] = sL2;
            aH = aH2; aL = aL2;
        }
    }

    #pragma unroll
    for (int t = 0; t < 4; t++) {
        const int col = mb * 64 + t * 16 + lr;
        const float bt = bias[col];
        #pragma unroll
        for (int reg = 0; reg < 4; reg++) {
            const int n = nstrip * 16 + lq * 4 + reg;
            Yf[(size_t)n * E_ + col] = acc[t][reg] + bt;
        }
    }
}

// ---------------------------------------------------------------------------
// Flash decay attention. XCD-AWARE SWIZZLE: bh = blockIdx & 31, so each XCD
// (blockIdx % 8 round-robin) sees only 4 bh pairs -> K/V working set 2.6 MB
// fits its 4 MB L2 (was 21 MB shared across all -> L2 thrash, 10.5 GB FETCH).
// ---------------------------------------------------------------------------
#define VPAD 72

__device__ __forceinline__ void score_tile(f32x4 (&a)[4],
    const ushort_t* __restrict__ Kbh, const ushort_t* __restrict__ Kbl,
    int jt, const bf16x8& qhi, const bf16x8& qlo, int lane, int lr, int lq,
    bool domask, int i0)
{
    #pragma unroll
    for (int tt = 0; tt < 4; tt++) {
        const size_t ko = (size_t)(jt * 4 + tt) * 512 + lane * 8;
        const bf16x8 khi = *(const bf16x8*)(Kbh + ko);
        const bf16x8 klo = *(const bf16x8*)(Kbl + ko);
        f32x4 v = {0.f, 0.f, 0.f, 0.f};
        v = __builtin_amdgcn_mfma_f32_16x16x32_bf16(qlo, khi, v, 0, 0, 0);
        v = __builtin_amdgcn_mfma_f32_16x16x32_bf16(qhi, klo, v, 0, 0, 0);
        v = __builtin_amdgcn_mfma_f32_16x16x32_bf16(qhi, khi, v, 0, 0, 0);
        a[tt] = v;
    }
    if (domask) {
        #pragma unroll
        for (int tt = 0; tt < 4; tt++)
            #pragma unroll
            for (int r = 0; r < 4; r++) {
                const int irow = i0 + lq * 4 + r;
                const int j    = jt * 64 + tt * 16 + lr;
                if (j > irow) a[tt][r] = -3.0e38f;
            }
    }
}

__global__ __launch_bounds__(256)
void attn_flash(const ushort_t* __restrict__ Qh, const ushort_t* __restrict__ Ql,
                const ushort_t* __restrict__ Kh, const ushort_t* __restrict__ Kl,
                const ushort_t* __restrict__ Vs, const float* __restrict__ gammas,
                ushort_t* __restrict__ Ch, ushort_t* __restrict__ Cl)
{
    __shared__ float sTS[16][36];
    __shared__ __align__(16) ushort_t sP[4][16 * VPAD];
    __shared__ float sO[4][16][32];
    __shared__ float sZ[4][16];

    const int tid  = threadIdx.x;
    const int lane = tid & 63, wv = tid >> 6;
    const int lr   = lane & 15, lq = lane >> 4;
    // XCD-aware decode: bh fastest (mod-8 residue pins bh set per XCD),
    // tq descending (longest first) in the slow dimension.
    const int bh   = blockIdx.x & 31;
    const int st   = (blockIdx.x >> 5) & 3;
    const int tq   = 31 - (blockIdx.x >> 7);
    const int h    = bh & 7, b = bh >> 3;
    const int i0   = tq * 64 + st * 16;

    const size_t hb = (size_t)bh * (S_ * DK_);
    const ushort_t* Kbh = Kh + hb;
    const ushort_t* Kbl = Kl + hb;
    const ushort_t* Vb  = Vs + hb;

    const float g   = gammas[h];
    const float gl2 = -((g > 20.f) ? g : log1pf(__expf(g))) * LOG2E;

    const size_t qoff = hb + (size_t)(i0 >> 4) * 512 + lane * 8;
    const bf16x8 qhi = *(const bf16x8*)(Qh + qoff);
    const bf16x8 qlo = *(const bf16x8*)(Ql + qoff);

    // ================= PASS A: per-tile raw exp row-sums ==================
    for (int jt = wv; jt <= tq; jt += 4) {
        f32x4 a[4];
        score_tile(a, Kbh, Kbl, jt, qhi, qlo, lane, lr, lq, jt == tq, i0);
        #pragma unroll
        for (int r = 0; r < 4; r++) {
            float rs = (EXP2F(a[0][r]) + EXP2F(a[1][r]))
                     + (EXP2F(a[2][r]) + EXP2F(a[3][r]));
            rs += __shfl_xor(rs, 1); rs += __shfl_xor(rs, 2);
            rs += __shfl_xor(rs, 4); rs += __shfl_xor(rs, 8);
            if (lr == 0) sTS[lq * 4 + r][jt] = rs;
        }
    }
    __syncthreads();

    // ================= PASS B (barrier-free per wave) =====================
    float z2a[4] = {0.f, 0.f, 0.f, 0.f};
    f32x4 O0 = {0.f,0.f,0.f,0.f}, O1 = {0.f,0.f,0.f,0.f};

    if (wv <= tq) {
        float invZ[4], base[4], pr[4];
        #pragma unroll
        for (int r = 0; r < 4; r++) {
            const int row = lq * 4 + r;
            float run = 0.f, bs = 0.f;
            for (int t = 0; t <= tq; t++) {
                if (t < wv) bs += sTS[row][t];
                run += sTS[row][t];
            }
            invZ[r] = RCPF(run);
            base[r] = bs;
            pr[r]   = (float)(i0 + row - lr);    // posf = pr - (j0 + tt*16)
        }

        ushort_t* sPw = &sP[wv][0];
        for (int jt = wv; jt <= tq; jt += 4) {
            const int j0 = jt * 64;
            f32x4 a[4];
            score_tile(a, Kbh, Kbl, jt, qhi, qlo, lane, lr, lq, jt == tq, i0);

            float sc[4][4], tot[4][4];
            #pragma unroll
            for (int tt = 0; tt < 4; tt++)
                #pragma unroll
                for (int r = 0; r < 4; r++) {
                    const float e = EXP2F(a[tt][r]);
                    const float s = scan16(e);
                    sc[tt][r]  = s;
                    tot[tt][r] = bcast15(s);
                }
            #pragma unroll
            for (int r = 0; r < 4; r++) {
                float run2 = base[r];
                #pragma unroll
                for (int tt = 0; tt < 4; tt++) { sc[tt][r] += run2; run2 += tot[tt][r]; }
            }
            #pragma unroll
            for (int tt = 0; tt < 4; tt++) {
                const float jf = (float)(j0 + tt * 16);
                #pragma unroll
                for (int r = 0; r < 4; r++) {
                    const float rest = fmaf(-sc[tt][r], invZ[r], 1.0f);
                    const float posf = pr[r] - jf;
                    const float dist = SQRTF(fmaxf(rest * posf, 0.f));
                    const float eff  = EXP2F(gl2 * dist);
                    const float p2   = EXP2F(a[tt][r] * eff);
                    z2a[r] += p2;
                    sPw[(lq * 4 + r) * VPAD + tt * 16 + lr] = bf16_rne(p2);
                }
            }
            #pragma unroll
            for (int kc = 0; kc < 2; kc++) {
                const bf16x8 pa = *(const bf16x8*)&sPw[lr * VPAD + kc * 32 + lq * 8];
                const size_t vb = (size_t)(((j0 >> 5) + kc) * 2) * 512 + lane * 8;
                const bf16x8 v0 = *(const bf16x8*)(Vb + vb);
                const bf16x8 v1 = *(const bf16x8*)(Vb + vb + 512);
                O0 = __builtin_amdgcn_mfma_f32_16x16x32_bf16(pa, v0, O0, 0, 0, 0);
                O1 = __builtin_amdgcn_mfma_f32_16x16x32_bf16(pa, v1, O1, 0, 0, 0);
            }
            if (jt + 4 <= tq) {
                #pragma unroll
                for (int r = 0; r < 4; r++) {
                    const int row = lq * 4 + r;
                    base[r] += sTS[row][jt] + sTS[row][jt+1] + sTS[row][jt+2] + sTS[row][jt+3];
                }
            }
        }
    }

    // ================= cross-wave reduce + output =========================
    #pragma unroll
    for (int r = 0; r < 4; r++) {
        float z = z2a[r];
        z += __shfl_xor(z, 1); z += __shfl_xor(z, 2);
        z += __shfl_xor(z, 4); z += __shfl_xor(z, 8);
        if (lr == 0) sZ[wv][lq * 4 + r] = z;
        sO[wv][lq * 4 + r][lr]      = O0[r];
        sO[wv][lq * 4 + r][16 + lr] = O1[r];
    }
    __syncthreads();

    #pragma unroll
    for (int p = 0; p < 2; p++) {
        const int pid = tid + p * 256;
        const int row = pid >> 5, d = pid & 31;
        const float v = (sO[0][row][d] + sO[1][row][d]) + (sO[2][row][d] + sO[3][row][d]);
        const float z = (sZ[0][row] + sZ[1][row]) + (sZ[2][row] + sZ[3][row]);
        const float y = v * RCPF(z);
        const int nIdx = b * S_ + i0 + row;
        const size_t o = ((size_t)(nIdx >> 4) * 8 + h) * 512
                       + (d >> 3) * 128 + (nIdx & 15) * 8 + (d & 7);
        const ushort_t hbb = bf16_rne(y);
        Ch[o] = hbb;
        Cl[o] = bf16_rne(y - bf16_to_f(hbb));
    }
}

// ---------------------------------------------------------------------------
extern "C" void kernel_launch(void* const* d_in, const int* in_sizes, int n_in,
                              void* d_out, int out_size, void* d_ws, size_t ws_size,
                              hipStream_t stream)
{
    const float* q      = (const float*)d_in[0];
    const float* k      = (const float*)d_in[1];
    const float* v      = (const float*)d_in[2];
    // d_in[3] = causal mask (analytic; unused)
    const float* Wq     = (const float*)d_in[4];
    const float* bq     = (const float*)d_in[5];
    const float* Wk     = (const float*)d_in[6];
    const float* bk     = (const float*)d_in[7];
    const float* Wv     = (const float*)d_in[8];
    const float* bv     = (const float*)d_in[9];
    const float* Wo     = (const float*)d_in[10];
    const float* bo     = (const float*)d_in[11];
    const float* gammas = (const float*)d_in[12];
    float* out = (float*)d_out;

    const size_t N2 = (size_t)NROWS * E_;      // 2,097,152 elements
    const size_t WN = (size_t)E_ * E_;         // 65,536

    ushort_t* wh = (ushort_t*)d_ws;            // 4*WN
    ushort_t* wl = wh + 4 * WN;                // 4*WN
    ushort_t* qh = wl + 4 * WN;
    ushort_t* ql = qh + N2;
    ushort_t* kh = ql + N2;
    ushort_t* kl = kh + N2;
    ushort_t* vt = kl + N2;
    ushort_t* ch = vt + N2;
    ushort_t* cl = ch + N2;

    conv_w<<<dim3(16, 4), 256, 0, stream>>>(Wq, Wk, Wv, Wo, wh, wl);

    gemm_qkv<<<dim3(E_ / 64, NROWS / 64, 3), 256, 0, stream>>>(
        q, k, v, wh, wl, bq, bk, bv, qh, ql, kh, kl, vt);

    attn_flash<<<32 * 32 * 4, 256, 0, stream>>>(qh, ql, kh, kl, vt, gammas, ch, cl);

    gemm_out<<<dim3(E_ / 64, NROWS / 64), 256, 0, stream>>>(
        ch, cl, wh + 3 * WN, wl + 3 * WN, bo, out);
}